// Round 4
// baseline (1192.859 us; speedup 1.0000x reference)
//
#include <hip/hip_runtime.h>

#define NTH 256
typedef __attribute__((ext_vector_type(2))) float f32x2;

// ---- d_ws layout (float/u32 indices, 4B units) ----
#define WS_WU    0       // f32 [32][32]  wuT[k*32+h]  = W3u[h][k]
#define WS_W5U   1024    // f32 [32][32]  w5uT[k*32+h] = W5u[h][k]
#define WS_WZ    2048    // f32 [2][32][32] wzT[s][k][h] = W3w[h][s*32+k]
#define WS_WR    4096    // f32 [2][32][32] from W4w
#define WS_WG    6144    // f32 [2][32][32] from W5w
#define WS_WO    8192    // f32 [64][16]  woT[k*16+j] = Wo[j][k]
#define WS_WRX   9216    // f32 [32][16]
#define WS_WRY   9728    // f32 [32][16]
#define WS_BZ    10240   // f32 [32] b3w+b3u
#define WS_BR    10272   // f32 [32] b4w+b3u
#define WS_BG    10304   // f32 [32] b5w+b5u
#define WS_BITC  10336   // u32 [16][4]  bit o of word (o>>5): mat[r][o]
#define WS_BITO  10400   // u32 [80]     bit c: mat[c][o]
#define WS_TOTAL 10480   // 41,920 bytes

__device__ __forceinline__ float sig_(float x) { return 1.0f / (1.0f + __expf(-x)); }
__device__ __forceinline__ float th_(float x)  { return 1.0f - 2.0f / (1.0f + __expf(2.0f * x)); }
__device__ __forceinline__ f32x2 sp(float x) { f32x2 r; r[0] = x; r[1] = x; return r; }
// v if bit set else +0.0f (exact)
__device__ __forceinline__ float msel(float v, unsigned bits, int bit) {
    const int m = (int)(bits << (31 - bit)) >> 31;
    return __int_as_float(__float_as_int(v) & m);
}

__global__ void ggnn_prep(const float* __restrict__ mask,
                          const float* __restrict__ W3w, const float* __restrict__ b3w,
                          const float* __restrict__ W3u, const float* __restrict__ b3u,
                          const float* __restrict__ W4w, const float* __restrict__ b4w,
                          const float* __restrict__ W5w, const float* __restrict__ b5w,
                          const float* __restrict__ W5u, const float* __restrict__ b5u,
                          const float* __restrict__ Wo,
                          const float* __restrict__ Wrx, const float* __restrict__ Wry,
                          float* __restrict__ ws)
{
    const int t = threadIdx.x;
    for (int i = t; i < 1024; i += NTH) {
        const int k = i >> 5, h = i & 31;
        ws[WS_WU  + i] = W3u[h*32 + k];
        ws[WS_W5U + i] = W5u[h*32 + k];
        ws[WS_WZ + i]        = W3w[h*64 + k];
        ws[WS_WZ + 1024 + i] = W3w[h*64 + 32 + k];
        ws[WS_WR + i]        = W4w[h*64 + k];
        ws[WS_WR + 1024 + i] = W4w[h*64 + 32 + k];
        ws[WS_WG + i]        = W5w[h*64 + k];
        ws[WS_WG + 1024 + i] = W5w[h*64 + 32 + k];
        const int kk = i >> 4, j = i & 15;
        ws[WS_WO + i] = Wo[j*64 + kk];
    }
    for (int i = t; i < 512; i += NTH) {
        const int k = i >> 4, j = i & 15;
        ws[WS_WRX + i] = Wrx[j*32 + k];
        ws[WS_WRY + i] = Wry[j*32 + k];
    }
    if (t < 32) {
        ws[WS_BZ + t] = b3w[t] + b3u[t];
        ws[WS_BR + t] = b4w[t] + b3u[t];
        ws[WS_BG + t] = b5w[t] + b5u[t];
    }
    unsigned* wsu = (unsigned*)ws;
    if (t < 64) {
        const int r = t >> 2, w = t & 3;
        unsigned bits = 0;
        for (int bb = 0; bb < 32; ++bb) {
            const int o = w*32 + bb;
            if (o < 80 && mask[r*80 + o] > 0.5f) bits |= (1u << bb);
        }
        wsu[WS_BITC + t] = bits;
    }
    if (t < 80) {
        unsigned bits = 0;
        for (int c = 0; c < 16; ++c)
            if (mask[c*80 + t] > 0.5f) bits |= (1u << c);
        wsu[WS_BITO + t] = bits;
    }
}

__global__ __launch_bounds__(NTH, 4)
void ggnn_main(const float* __restrict__ input, const float* __restrict__ ws,
               const float* __restrict__ bo,  const float* __restrict__ brx,
               const float* __restrict__ bry, const float* __restrict__ Wr2,
               const float* __restrict__ br2, float* __restrict__ dout)
{
    __shared__ float S[6336];           // 25,344 B
    float* NOD = S;                     // [96][33]
    float* AV  = S + 3168;              // [96][33] (rn / x0 / OUTB overlay)
    const int tid = threadIdx.x;
    const int b   = blockIdx.x;
    const float* xin = input + (size_t)b * 3072;
    const unsigned* wsu = (const unsigned*)ws;

    for (int t = tid; t < 3072; t += NTH)
        NOD[(t >> 5)*33 + (t & 31)] = xin[t];

    const int a  = tid & 31;
    const int bq = tid >> 5;
    const int h0 = bq << 2;
    const int i0 = a, i1 = a + 32, i2 = a + 64;
    const int sel0 = (a < 16) ? 0 : 1024;

    const float* wuB  = ws + WS_WU + h0;
    const float* wzB0 = ws + WS_WZ + sel0 + h0;
    const float* wzBO = ws + WS_WZ + 1024 + h0;
    const float* wrB0 = ws + WS_WR + sel0 + h0;
    const float* wrBO = ws + WS_WR + 1024 + h0;
    const float* wgB0 = ws + WS_WG + sel0 + h0;
    const float* wgBO = ws + WS_WG + 1024 + h0;
    const float* w5B  = ws + WS_W5U + h0;

    __syncthreads();

    for (int it = 0; it < 5; ++it) {
        {   // ---- phase A: adjacency matvec via bitmasks ----
            unsigned bc0[3], bc1[3];
            #pragma unroll
            for (int w = 0; w < 3; ++w) {
                bc0[w] = wsu[WS_BITC + bq*4 + w];
                bc1[w] = wsu[WS_BITC + (bq + 8)*4 + w];
            }
            float a0 = 0.f, a1 = 0.f;
            #pragma unroll
            for (int o = 0; o < 80; ++o) {
                const float v = NOD[(16 + o)*33 + a];
                a0 += msel(v, bc0[o >> 5], o & 31);
                a1 += msel(v, bc1[o >> 5], o & 31);
            }
            AV[bq*33 + a]       = a0;
            AV[(bq + 8)*33 + a] = a1;
            float vc[16];
            #pragma unroll
            for (int c = 0; c < 16; ++c) vc[c] = NOD[c*33 + a];
            #pragma unroll
            for (int t = 0; t < 10; ++t) {
                const unsigned bb = wsu[WS_BITO + bq + 8*t];
                float acc = 0.f;
                #pragma unroll
                for (int c = 0; c < 16; ++c) acc += msel(vc[c], bb, c);
                AV[(16 + bq + 8*t)*33 + a] = acc;
            }
        }
        __syncthreads();

        // ---- pass 1: u3, z, r, g(av-part); packed f32 ----
        const f32x2 bzA = *(const f32x2*)(ws + WS_BZ + h0);
        const f32x2 bzB = *(const f32x2*)(ws + WS_BZ + h0 + 2);
        const f32x2 brA = *(const f32x2*)(ws + WS_BR + h0);
        const f32x2 brB = *(const f32x2*)(ws + WS_BR + h0 + 2);
        const f32x2 bgA = *(const f32x2*)(ws + WS_BG + h0);
        const f32x2 bgB = *(const f32x2*)(ws + WS_BG + h0 + 2);
        f32x2 u0A = sp(0.f), u0B = sp(0.f), u1A = sp(0.f), u1B = sp(0.f), u2A = sp(0.f), u2B = sp(0.f);
        f32x2 z0A = bzA, z0B = bzB, z1A = bzA, z1B = bzB, z2A = bzA, z2B = bzB;
        f32x2 r0A = brA, r0B = brB, r1A = brA, r1B = brB, r2A = brA, r2B = brB;
        f32x2 g0A = bgA, g0B = bgB, g1A = bgA, g1B = bgB, g2A = bgA, g2B = bgB;
        #pragma unroll 2
        for (int k = 0; k < 32; ++k) {
            const int ko = k*32;
            union { float4 v; f32x2 h[2]; } wu, wz0, wzO, wr0, wrO, wg0, wgO;
            wu.v  = *(const float4*)(wuB  + ko);
            wz0.v = *(const float4*)(wzB0 + ko);
            wzO.v = *(const float4*)(wzBO + ko);
            wr0.v = *(const float4*)(wrB0 + ko);
            wrO.v = *(const float4*)(wrBO + ko);
            wg0.v = *(const float4*)(wgB0 + ko);
            wgO.v = *(const float4*)(wgBO + ko);
            const f32x2 n0 = sp(NOD[i0*33 + k]), n1 = sp(NOD[i1*33 + k]), n2 = sp(NOD[i2*33 + k]);
            const f32x2 v0 = sp(AV[i0*33 + k]),  v1 = sp(AV[i1*33 + k]),  v2 = sp(AV[i2*33 + k]);
            u0A += wu.h[0]*n0;  u0B += wu.h[1]*n0;
            u1A += wu.h[0]*n1;  u1B += wu.h[1]*n1;
            u2A += wu.h[0]*n2;  u2B += wu.h[1]*n2;
            z0A += wz0.h[0]*v0; z0B += wz0.h[1]*v0;
            z1A += wzO.h[0]*v1; z1B += wzO.h[1]*v1;
            z2A += wzO.h[0]*v2; z2B += wzO.h[1]*v2;
            r0A += wr0.h[0]*v0; r0B += wr0.h[1]*v0;
            r1A += wrO.h[0]*v1; r1B += wrO.h[1]*v1;
            r2A += wrO.h[0]*v2; r2B += wrO.h[1]*v2;
            g0A += wg0.h[0]*v0; g0B += wg0.h[1]*v0;
            g1A += wgO.h[0]*v1; g1B += wgO.h[1]*v1;
            g2A += wgO.h[0]*v2; g2B += wgO.h[1]*v2;
        }
        float uu0[4] = {u0A[0], u0A[1], u0B[0], u0B[1]};
        float uu1[4] = {u1A[0], u1A[1], u1B[0], u1B[1]};
        float uu2[4] = {u2A[0], u2A[1], u2B[0], u2B[1]};
        float zz0[4] = {z0A[0], z0A[1], z0B[0], z0B[1]};
        float zz1[4] = {z1A[0], z1A[1], z1B[0], z1B[1]};
        float zz2[4] = {z2A[0], z2A[1], z2B[0], z2B[1]};
        float rr0[4] = {r0A[0], r0A[1], r0B[0], r0B[1]};
        float rr1[4] = {r1A[0], r1A[1], r1B[0], r1B[1]};
        float rr2[4] = {r2A[0], r2A[1], r2B[0], r2B[1]};
        float nd0[4], nd1[4], nd2[4], rn0[4], rn1[4], rn2[4];
        #pragma unroll
        for (int q = 0; q < 4; ++q) {
            nd0[q] = NOD[i0*33 + h0 + q];
            nd1[q] = NOD[i1*33 + h0 + q];
            nd2[q] = NOD[i2*33 + h0 + q];
            zz0[q] = sig_(zz0[q] + uu0[q]);
            zz1[q] = sig_(zz1[q] + uu1[q]);
            zz2[q] = sig_(zz2[q] + uu2[q]);
            rn0[q] = sig_(rr0[q] + uu0[q]) * nd0[q];
            rn1[q] = sig_(rr1[q] + uu1[q]) * nd1[q];
            rn2[q] = sig_(rr2[q] + uu2[q]) * nd2[q];
        }
        __syncthreads();                    // av reads done -> overlay rn
        #pragma unroll
        for (int q = 0; q < 4; ++q) {
            AV[i0*33 + h0 + q] = rn0[q];
            AV[i1*33 + h0 + q] = rn1[q];
            AV[i2*33 + h0 + q] = rn2[q];
        }
        __syncthreads();

        // ---- pass 2: g += rn @ W5u^T ; update ----
        #pragma unroll 2
        for (int k = 0; k < 32; ++k) {
            union { float4 v; f32x2 h[2]; } w5;
            w5.v = *(const float4*)(w5B + k*32);
            const f32x2 q0 = sp(AV[i0*33 + k]), q1 = sp(AV[i1*33 + k]), q2 = sp(AV[i2*33 + k]);
            g0A += w5.h[0]*q0; g0B += w5.h[1]*q0;
            g1A += w5.h[0]*q1; g1B += w5.h[1]*q1;
            g2A += w5.h[0]*q2; g2B += w5.h[1]*q2;
        }
        float gg0[4] = {g0A[0], g0A[1], g0B[0], g0B[1]};
        float gg1[4] = {g1A[0], g1A[1], g1B[0], g1B[1]};
        float gg2[4] = {g2A[0], g2A[1], g2B[0], g2B[1]};
        #pragma unroll
        for (int q = 0; q < 4; ++q) {
            NOD[i0*33 + h0 + q] = fmaf(zz0[q], th_(gg0[q]) - nd0[q], nd0[q]);
            NOD[i1*33 + h0 + q] = fmaf(zz1[q], th_(gg1[q]) - nd1[q], nd1[q]);
            NOD[i2*33 + h0 + q] = fmaf(zz2[q], th_(gg2[q]) - nd2[q], nd2[q]);
        }
        __syncthreads();
    }

    // ---------------- head ----------------
    for (int t = tid; t < 3072; t += NTH)       // x0 -> AV region
        AV[(t >> 5)*33 + (t & 31)] = xin[t];
    __syncthreads();

    // out = tanh([nodes, x0] @ Wo^T + bo): thread = 3 rows x 2 j (packed)
    const int j2 = bq * 2;
    f32x2 oa0 = *(const f32x2*)(bo + j2);
    f32x2 oa1 = oa0, oa2 = oa0;
    #pragma unroll 2
    for (int k = 0; k < 32; ++k) {
        const f32x2 wn = *(const f32x2*)(ws + WS_WO + k*16 + j2);
        const f32x2 wx = *(const f32x2*)(ws + WS_WO + (32 + k)*16 + j2);
        const f32x2 n0 = sp(NOD[i0*33 + k]), n1 = sp(NOD[i1*33 + k]), n2 = sp(NOD[i2*33 + k]);
        const f32x2 x0 = sp(AV[i0*33 + k]),  x1 = sp(AV[i1*33 + k]),  x2 = sp(AV[i2*33 + k]);
        oa0 += wn*n0; oa0 += wx*x0;
        oa1 += wn*n1; oa1 += wx*x1;
        oa2 += wn*n2; oa2 += wx*x2;
    }
    const float ob0[2] = {th_(oa0[0]), th_(oa0[1])};
    const float ob1[2] = {th_(oa1[0]), th_(oa1[1])};
    const float ob2[2] = {th_(oa2[0]), th_(oa2[1])};

    // rfcx / rfcy into registers
    const int jj = tid & 15, grp = tid >> 4;
    float ax = brx[jj];
    #pragma unroll 4
    for (int k = 0; k < 32; ++k)
        ax = fmaf(ws[WS_WRX + k*16 + jj], NOD[grp*33 + k], ax);
    float ay[5];
    #pragma unroll
    for (int t2 = 0; t2 < 5; ++t2) ay[t2] = bry[jj];
    #pragma unroll 2
    for (int k = 0; k < 32; ++k) {
        const float ww = ws[WS_WRY + k*16 + jj];
        #pragma unroll
        for (int t2 = 0; t2 < 5; ++t2)
            ay[t2] = fmaf(ww, NOD[(16 + grp + 16*t2)*33 + k], ay[t2]);
    }
    __syncthreads();    // all NOD/x0 reads done -> overlay

    // OUTB [96][20] over AV; RFCX[16][17]@NOD+0; RFCY[80][17]@NOD+272; RFC2[16][80]@NOD+1632
    #pragma unroll
    for (int q = 0; q < 2; ++q) {
        AV[i0*20 + j2 + q] = ob0[q];
        AV[i1*20 + j2 + q] = ob1[q];
        AV[i2*20 + j2 + q] = ob2[q];
    }
    NOD[grp*17 + jj] = th_(ax);
    #pragma unroll
    for (int t2 = 0; t2 < 5; ++t2)
        NOD[272 + (grp + 16*t2)*17 + jj] = th_(ay[t2]);
    __syncthreads();

    {   // rfc2 = sigmoid(sum_j Wr2[j]*rfcx[c][j]*rfcy[o][j] + br2) * mask
        float wr2r[16];
        #pragma unroll
        for (int j = 0; j < 16; ++j) wr2r[j] = Wr2[j];
        const float br2v = br2[0];
        #pragma unroll
        for (int t2 = 0; t2 < 5; ++t2) {
            const int idx = tid + NTH*t2;       // 0..1279
            const int c = idx / 80;
            const int o = idx - c*80;
            float s = br2v;
            #pragma unroll
            for (int j = 0; j < 16; ++j)
                s = fmaf(wr2r[j], NOD[c*17 + j] * NOD[272 + o*17 + j], s);
            NOD[1632 + idx] = msel(sig_(s), wsu[WS_BITO + o], c);
        }
    }
    __syncthreads();

    {   // final stores: (16, 81, 16), coalesced float4
        float* doutb = dout + (size_t)b * 20736;
        #pragma unroll
        for (int t2 = 0; t2 < 21; ++t2) {
            const int f4 = tid + NTH*t2;        // 0..5183
            if (f4 < 5184) {
                const int f   = f4 << 2;
                const int c   = f / 1296;
                const int rem = f - c*1296;
                const int co  = rem >> 4;
                const int k   = rem & 15;
                float4 v;
                if (co == 0) {
                    v = *(const float4*)&AV[c*20 + k];
                } else {
                    const float sc = NOD[1632 + c*80 + (co - 1)];
                    const float4 ov = *(const float4*)&AV[(16 + co - 1)*20 + k];
                    v.x = ov.x*sc; v.y = ov.y*sc; v.z = ov.z*sc; v.w = ov.w*sc;
                }
                *(float4*)&doutb[f] = v;
            }
        }
    }
}

extern "C" void kernel_launch(void* const* d_in, const int* in_sizes, int n_in,
                              void* d_out, int out_size, void* d_ws, size_t ws_size,
                              hipStream_t stream) {
    const float* input = (const float*)d_in[0];
    const float* maskp = (const float*)d_in[3];
    const float* W3w = (const float*)d_in[4];  const float* b3w = (const float*)d_in[5];
    const float* W3u = (const float*)d_in[6];  const float* b3u = (const float*)d_in[7];
    const float* W4w = (const float*)d_in[8];  const float* b4w = (const float*)d_in[9];
    const float* W5w = (const float*)d_in[10]; const float* b5w = (const float*)d_in[11];
    const float* W5u = (const float*)d_in[12]; const float* b5u = (const float*)d_in[13];
    const float* Wo  = (const float*)d_in[14]; const float* bo  = (const float*)d_in[15];
    const float* Wrx = (const float*)d_in[16]; const float* brx = (const float*)d_in[17];
    const float* Wry = (const float*)d_in[18]; const float* bry = (const float*)d_in[19];
    const float* Wr2 = (const float*)d_in[20]; const float* br2 = (const float*)d_in[21];
    float* ws = (float*)d_ws;

    ggnn_prep<<<dim3(1), dim3(NTH), 0, stream>>>(
        maskp, W3w, b3w, W3u, b3u, W4w, b4w, W5w, b5w, W5u, b5u, Wo, Wrx, Wry, ws);
    ggnn_main<<<dim3(4096), dim3(NTH), 0, stream>>>(
        input, ws, bo, brx, bry, Wr2, br2, (float*)d_out);
}